// Round 1
// baseline (18810.252 us; speedup 1.0000x reference)
//
#include <hip/hip_runtime.h>
#include <hip/hip_bf16.h>

typedef __attribute__((ext_vector_type(4))) float  fvec4;
typedef __attribute__((ext_vector_type(8))) short  svec8;    // 8 bf16 (4 VGPRs), MFMA A/B frag
typedef __attribute__((ext_vector_type(8))) unsigned short usvec8;
typedef __attribute__((ext_vector_type(4))) unsigned short usvec4;
typedef __attribute__((ext_vector_type(4))) unsigned int   uivec4;

#define MFMA16 __builtin_amdgcn_mfma_f32_16x16x32_bf16

static __device__ __forceinline__ unsigned short f2bf(float f) {
    __hip_bfloat16 h = __float2bfloat16(f);
    return __builtin_bit_cast(unsigned short, h);
}
static __device__ __forceinline__ float bf2f(unsigned short u) {
    unsigned int v = ((unsigned int)u) << 16;
    return __builtin_bit_cast(float, v);
}
// XOR-swizzle of byte-offset-within-row (rows are 1024B): spreads 16-row column
// reads across banks; 16B-aligned offsets stay 16B-aligned.
static __device__ __forceinline__ int swz(int row, int byteincol) {
    return byteincol ^ ((row & 7) << 4);
}

// ---------------- fp32 -> bf16 convert ----------------
__global__ void cvt_kernel(const float* __restrict__ in, unsigned short* __restrict__ out, int n4) {
    int stride = gridDim.x * blockDim.x;
    for (int i = blockIdx.x * blockDim.x + threadIdx.x; i < n4; i += stride) {
        fvec4 v = ((const fvec4*)in)[i];
        usvec4 u;
        u[0] = f2bf(v[0]); u[1] = f2bf(v[1]); u[2] = f2bf(v[2]); u[3] = f2bf(v[3]);
        ((usvec4*)out)[i] = u;
    }
}

// ---------------- GEMM: out[m][n] = sum_k lhs[m][k] * rhs[n][k], K=N=512 ----------------
// LHS_F32_PERM: lhs is float x[b][t][k], row m -> (b=m&15, t=m>>4), convert to bf16 while staging.
//               else lhs is bf16 [m][512].
// OUT_PERM:     out is float, row m stored at (m&15)*4096 + (m>>4).  else out is bf16 [m][512].
template<bool LHS_F32_PERM, bool OUT_PERM>
__global__ __launch_bounds__(256)
void gemm512(const void* __restrict__ lhsv, const unsigned short* __restrict__ rhs,
             void* __restrict__ outv)
{
    __shared__ __align__(16) unsigned short smA[64 * 72];
    __shared__ __align__(16) unsigned short smB[64 * 72];
    const int tid = threadIdx.x;
    const int m0 = blockIdx.x * 64;
    const int n0 = blockIdx.y * 64;
    const int w = tid >> 6, l = tid & 63;
    const int g = l >> 4, r16 = l & 15;
    const int wm = (w >> 1) * 32, wn = (w & 1) * 32;
    const int ri = tid >> 2;            // staging row 0..63
    const int kseg = (tid & 3) * 16;    // staging k segment

    fvec4 acc[2][2] = {};

    for (int k0 = 0; k0 < 512; k0 += 64) {
        // ---- stage LHS tile ----
        if (LHS_F32_PERM) {
            const float* x = (const float*)lhsv;
            int m = m0 + ri;
            size_t base = ((size_t)(m & 15) * 4096 + (size_t)(m >> 4)) * 512 + k0 + kseg;
            usvec8 o0, o1;
            fvec4 v0 = *(const fvec4*)(x + base + 0);
            fvec4 v1 = *(const fvec4*)(x + base + 4);
            fvec4 v2 = *(const fvec4*)(x + base + 8);
            fvec4 v3 = *(const fvec4*)(x + base + 12);
            o0[0]=f2bf(v0[0]); o0[1]=f2bf(v0[1]); o0[2]=f2bf(v0[2]); o0[3]=f2bf(v0[3]);
            o0[4]=f2bf(v1[0]); o0[5]=f2bf(v1[1]); o0[6]=f2bf(v1[2]); o0[7]=f2bf(v1[3]);
            o1[0]=f2bf(v2[0]); o1[1]=f2bf(v2[1]); o1[2]=f2bf(v2[2]); o1[3]=f2bf(v2[3]);
            o1[4]=f2bf(v3[0]); o1[5]=f2bf(v3[1]); o1[6]=f2bf(v3[2]); o1[7]=f2bf(v3[3]);
            *(usvec8*)(smA + ri * 72 + kseg)     = o0;
            *(usvec8*)(smA + ri * 72 + kseg + 8) = o1;
        } else {
            const unsigned short* s = (const unsigned short*)lhsv;
            size_t base = (size_t)(m0 + ri) * 512 + k0 + kseg;
            *(usvec8*)(smA + ri * 72 + kseg)     = *(const usvec8*)(s + base);
            *(usvec8*)(smA + ri * 72 + kseg + 8) = *(const usvec8*)(s + base + 8);
        }
        // ---- stage RHS tile ----
        {
            size_t base = (size_t)(n0 + ri) * 512 + k0 + kseg;
            *(usvec8*)(smB + ri * 72 + kseg)     = *(const usvec8*)(rhs + base);
            *(usvec8*)(smB + ri * 72 + kseg + 8) = *(const usvec8*)(rhs + base + 8);
        }
        __syncthreads();
        #pragma unroll
        for (int kt = 0; kt < 2; ++kt) {
            svec8 a0 = *(const svec8*)(smA + (wm +      r16) * 72 + 32 * kt + 8 * g);
            svec8 a1 = *(const svec8*)(smA + (wm + 16 + r16) * 72 + 32 * kt + 8 * g);
            svec8 b0 = *(const svec8*)(smB + (wn +      r16) * 72 + 32 * kt + 8 * g);
            svec8 b1 = *(const svec8*)(smB + (wn + 16 + r16) * 72 + 32 * kt + 8 * g);
            acc[0][0] = MFMA16(a0, b0, acc[0][0], 0, 0, 0);
            acc[0][1] = MFMA16(a0, b1, acc[0][1], 0, 0, 0);
            acc[1][0] = MFMA16(a1, b0, acc[1][0], 0, 0, 0);
            acc[1][1] = MFMA16(a1, b1, acc[1][1], 0, 0, 0);
        }
        __syncthreads();
    }
    // ---- epilogue: C/D map col=lane&15, row=(lane>>4)*4+reg ----
    #pragma unroll
    for (int mt = 0; mt < 2; ++mt)
    #pragma unroll
    for (int nt = 0; nt < 2; ++nt)
    #pragma unroll
    for (int r = 0; r < 4; ++r) {
        int m = m0 + wm + 16 * mt + 4 * g + r;
        int n = n0 + wn + 16 * nt + r16;
        float v = acc[mt][nt][r];
        if (OUT_PERM) {
            float* out = (float*)outv;
            out[((size_t)(m & 15) * 4096 + (size_t)(m >> 4)) * 512 + n] = v;
        } else {
            unsigned short* out = (unsigned short*)outv;
            out[(size_t)m * 512 + n] = f2bf(v);
        }
    }
}

// ---------------- recurrence: 4 WGs, each owns 128 cols of A in VGPRs ----------------
// states[t*16+b][n] bf16 doubles as the cross-WG exchange buffer and the LHS of the final GEMM.
#define RT 4096
__global__ __launch_bounds__(256)
void recur_kernel(const unsigned short* __restrict__ Abf,   // [512][512] bf16, A[n][k]
                  const unsigned short* __restrict__ bx,    // [65536][512] bf16, row = t*16+b
                  unsigned short* __restrict__ states,      // [65536][512] bf16, row = t*16+b
                  int* __restrict__ flags)                  // [4096][4], zeroed per launch
{
    __shared__ __align__(16) unsigned short st[2][16 * 512];   // swizzled [b][k]
    const int wg  = blockIdx.x;      // 0..3
    const int tid = threadIdx.x;
    const int w = tid >> 6, l = tid & 63;
    const int g = l >> 4, r16 = l & 15;
    const int colbase = wg * 128 + w * 32;     // + nt*16 + r16
    const int irow = tid >> 4;                 // import/export row 0..15
    const int ich  = tid & 15;                 // 16B chunk 0..15

    // ---- preload this wave's A fragments (B-operand): lane: n=colbase+16nt+r16, k=32kt+8g+e
    svec8 af[16][2];
    #pragma unroll
    for (int kt = 0; kt < 16; ++kt) {
        #pragma unroll
        for (int nt = 0; nt < 2; ++nt)
            af[kt][nt] = *(const svec8*)(Abf + (size_t)(colbase + 16 * nt + r16) * 512 + 32 * kt + 8 * g);
    }

    // ---- t = 0: state0 = relu(bx[0]) ----
    float vcur[2][4];
    #pragma unroll
    for (int nt = 0; nt < 2; ++nt)
        #pragma unroll
        for (int r = 0; r < 4; ++r)
            vcur[nt][r] = bf2f(bx[(size_t)(4 * g + r) * 512 + colbase + 16 * nt + r16]);
    unsigned short pn[2][4];   // prefetch regs for bx[t]
    #pragma unroll
    for (int nt = 0; nt < 2; ++nt)
        #pragma unroll
        for (int r = 0; r < 4; ++r)
            pn[nt][r] = bx[(size_t)(16 + 4 * g + r) * 512 + colbase + 16 * nt + r16];

    #pragma unroll
    for (int nt = 0; nt < 2; ++nt)
        #pragma unroll
        for (int r = 0; r < 4; ++r) {
            float f = fmaxf(vcur[nt][r], 0.0f);
            int row = 4 * g + r;
            int n = colbase + 16 * nt + r16;
            *(unsigned short*)((char*)&st[0][0] + row * 1024 + swz(row, 2 * n)) = f2bf(f);
        }
    __syncthreads();
    {   // export own slice of state_0
        uivec4 val = *(const uivec4*)((const char*)&st[0][0] + irow * 1024 + swz(irow, wg * 256 + ich * 16));
        *(uivec4*)((char*)states + (size_t)irow * 1024 + wg * 256 + ich * 16) = val;
    }
    __threadfence();
    __syncthreads();
    if (tid == 0)
        __hip_atomic_store(&flags[0 * 4 + wg], 1, __ATOMIC_RELEASE, __HIP_MEMORY_SCOPE_AGENT);

    // ---- main loop ----
    for (int t = 1; t < RT; ++t) {
        const int p = (t - 1) & 1, q = t & 1;

        // consume prefetched bx[t]; issue prefetch for bx[t+1]
        #pragma unroll
        for (int nt = 0; nt < 2; ++nt)
            #pragma unroll
            for (int r = 0; r < 4; ++r)
                vcur[nt][r] = bf2f(pn[nt][r]);
        if (t + 1 < RT) {
            #pragma unroll
            for (int nt = 0; nt < 2; ++nt)
                #pragma unroll
                for (int r = 0; r < 4; ++r)
                    pn[nt][r] = bx[(size_t)((t + 1) * 16 + 4 * g + r) * 512 + colbase + 16 * nt + r16];
        }

        // poll peers' flags for state_{t-1} (bounded spin: no hang on sync bug)
        if (l < 4 && l != wg) {
            const int* fp = &flags[(t - 1) * 4 + l];
            int cnt = 0;
            while (__hip_atomic_load(fp, __ATOMIC_ACQUIRE, __HIP_MEMORY_SCOPE_AGENT) == 0) {
                __builtin_amdgcn_s_sleep(1);
                if (++cnt > (1 << 17)) break;
            }
        }
        __threadfence();

        // import peers' 3 slices of state_{t-1} into st[p]
        #pragma unroll
        for (int j = 0; j < 4; ++j) {
            if (j == wg) continue;
            uivec4 val = *(const uivec4*)((const char*)states
                            + (size_t)(16 * (t - 1) + irow) * 1024 + j * 256 + ich * 16);
            *(uivec4*)((char*)&st[p][0] + irow * 1024 + swz(irow, j * 256 + ich * 16)) = val;
        }
        __syncthreads();   // B1: state_{t-1} fully in LDS

        // MFMA: acc[nt] init = bx[t]; A_op = state frag (row=l&15, k=32kt+8g+e), B_op = af
        fvec4 acc0 = { vcur[0][0], vcur[0][1], vcur[0][2], vcur[0][3] };
        fvec4 acc1 = { vcur[1][0], vcur[1][1], vcur[1][2], vcur[1][3] };
        #pragma unroll
        for (int kt = 0; kt < 16; ++kt) {
            svec8 sa = *(const svec8*)((const char*)&st[p][0] + r16 * 1024 + swz(r16, 64 * kt + 16 * g));
            acc0 = MFMA16(sa, af[kt][0], acc0, 0, 0, 0);
            acc1 = MFMA16(sa, af[kt][1], acc1, 0, 0, 0);
        }
        __syncthreads();   // B2: everyone done reading st[p]... and st[q] from step t-1

        // relu + cvt + write own slice into st[q]
        #pragma unroll
        for (int nt = 0; nt < 2; ++nt)
            #pragma unroll
            for (int r = 0; r < 4; ++r) {
                float f = fmaxf(nt ? acc1[r] : acc0[r], 0.0f);
                int row = 4 * g + r;
                int n = colbase + 16 * nt + r16;
                *(unsigned short*)((char*)&st[q][0] + row * 1024 + swz(row, 2 * n)) = f2bf(f);
            }
        __syncthreads();   // B3: own slice complete in LDS

        // export own slice to global states[t]
        {
            uivec4 val = *(const uivec4*)((const char*)&st[q][0] + irow * 1024 + swz(irow, wg * 256 + ich * 16));
            *(uivec4*)((char*)states + (size_t)(16 * t + irow) * 1024 + wg * 256 + ich * 16) = val;
        }
        __threadfence();
        __syncthreads();   // B4: all threads' stores fenced before flag
        if (tid == 0)
            __hip_atomic_store(&flags[t * 4 + wg], 1, __ATOMIC_RELEASE, __HIP_MEMORY_SCOPE_AGENT);
    }
}

extern "C" void kernel_launch(void* const* d_in, const int* in_sizes, int n_in,
                              void* d_out, int out_size, void* d_ws, size_t ws_size,
                              hipStream_t stream) {
    const float* x = (const float*)d_in[0];   // [16][4096][512]
    const float* A = (const float*)d_in[1];   // [512][512]
    const float* B = (const float*)d_in[2];   // [512][512]
    const float* C = (const float*)d_in[3];   // [512][512]
    float* out = (float*)d_out;               // [16][4096][512]

    char* ws = (char*)d_ws;
    unsigned short* Abf = (unsigned short*)(ws + 0);                          // 512KB
    unsigned short* Bbf = (unsigned short*)(ws + (size_t)(1 << 19));          // 512KB
    unsigned short* Cbf = (unsigned short*)(ws + (size_t)(2 << 19));          // 512KB
    unsigned short* bx  = (unsigned short*)(ws + (size_t)(4 << 19));          // 64MB: [65536][512] bf16
    unsigned short* states = (unsigned short*)(ws + (size_t)(4 << 19) + ((size_t)1 << 26)); // 64MB
    int* flags = (int*)(ws + (size_t)(4 << 19) + ((size_t)2 << 26));          // 64KB

    hipMemsetAsync(flags, 0, 4096 * 4 * sizeof(int), stream);
    cvt_kernel<<<64, 256, 0, stream>>>(A, Abf, 512 * 512 / 4);
    cvt_kernel<<<64, 256, 0, stream>>>(B, Bbf, 512 * 512 / 4);
    cvt_kernel<<<64, 256, 0, stream>>>(C, Cbf, 512 * 512 / 4);

    dim3 grid(1024, 8);
    // bx[t*16+b][n] = sum_d x[b][t][d] * B[n][d]
    gemm512<true, false><<<grid, 256, 0, stream>>>((const void*)x, Bbf, (void*)bx);
    // sequential recurrence, states[t*16+b][n]
    recur_kernel<<<4, 256, 0, stream>>>(Abf, bx, states, flags);
    // y[b][t][j] = sum_n states[t*16+b][n] * C[j][n]
    gemm512<false, true><<<grid, 256, 0, stream>>>((const void*)states, Cbf, (void*)out);
}